// Round 1
// 779.108 us; speedup vs baseline: 1.0265x; 1.0265x over previous
//
#include <hip/hip_runtime.h>
#include <hip/hip_bf16.h>
#include <stdint.h>

// Problem constants (QRNN layer: SEQ=4096, BATCH=8, IN=1024, HID=1024)
#define S_   4096
#define B_   8
#define IN_  1024
#define H_   1024
#define M_   (S_ * B_)     // 32768 rows of the GEMM (row = s*B + b)
#define N_   (3 * H_)      // 3072 output cols (Z | F | O)
#define K_   IN_           // 1024
#define CH_  (B_ * H_)     // 8192 independent scan channels
#define NC_  64            // scan chunks
#define T_   (S_ / NC_)    // 64 steps per chunk

typedef unsigned short u16;
typedef __bf16 bf16x8 __attribute__((ext_vector_type(8)));
typedef float  f32x4  __attribute__((ext_vector_type(4)));

__device__ __forceinline__ u16 f2bf(float f) {
  unsigned u = __float_as_uint(f);
  u += 0x7fffu + ((u >> 16) & 1u);   // round-to-nearest-even
  return (u16)(u >> 16);
}

__device__ __forceinline__ float sigmoid_(float x) { return 1.0f / (1.0f + __expf(-x)); }
__device__ __forceinline__ float tanh_(float x)    { return 2.0f / (1.0f + __expf(-2.0f * x)) - 1.0f; }

// ---- fp32 -> bf16 conversion, 8 elems/thread --------------------------------
__global__ void cvt_bf16_kernel(const float* __restrict__ in, u16* __restrict__ out, int n8) {
  int i = blockIdx.x * blockDim.x + threadIdx.x;
  if (i >= n8) return;
  const float4* p = (const float4*)in;
  float4 a = p[2 * i], b = p[2 * i + 1];
  alignas(16) u16 us[8] = {f2bf(a.x), f2bf(a.y), f2bf(a.z), f2bf(a.w),
                           f2bf(b.x), f2bf(b.y), f2bf(b.z), f2bf(b.w)};
  ((uint4*)out)[i] = *(const uint4*)us;
}

// ---- bf16 MFMA GEMM (NT: C[m][n] = sum_k A[m][k]*B[n][k]) + fused activation
// 128x128 tile, BK=64, 256 threads = 4 waves, each wave 64x64 via 4x4 16x16x32.
// XCD-aware bijective block remap: 24 consecutive work-ids share one A-panel;
// grouping them on one XCD keeps the 256 KiB panel L2-resident.
__global__ void gemm_act(const u16* __restrict__ Ab, const u16* __restrict__ Bb,
                         const float* __restrict__ bias,
                         float* __restrict__ zt,   // tanh(Z)  -> ws        [M_, H_]
                         float* __restrict__ Cf,   // sigm(F)  -> C region  [M_, H_]
                         float* __restrict__ Ho) { // sigm(O)  -> H region  [M_, H_]
  __shared__ alignas(16) u16 As[128 * 64];
  __shared__ alignas(16) u16 Bs[128 * 64];
  const int t = threadIdx.x;
  const int w = t >> 6, l = t & 63;
  // nwg = 24*256 = 6144; 6144 % 8 == 0 -> simple bijective XCD swizzle valid.
  const int d  = blockIdx.y * gridDim.x + blockIdx.x;           // dispatch id
  const int wk = (d & 7) * ((N_ / 128) * (M_ / 128) / 8) + (d >> 3);
  const int m0 = (wk / (N_ / 128)) * 128;
  const int n0 = (wk % (N_ / 128)) * 128;
  const int wm = (w & 1) * 64, wn = (w >> 1) * 64;
  const int r  = l & 15;            // M-index (A frag) / N-index (B frag) within 16
  const int ko = (l >> 4) * 8;      // K sub-offset within 32
  const int lrow = l >> 3;          // staging: row within 8-row segment
  const int lcol = (l & 7) * 8;     // staging: K col offset

  f32x4 acc[4][4];
#pragma unroll
  for (int i = 0; i < 4; ++i)
#pragma unroll
    for (int j = 0; j < 4; ++j) acc[i][j] = (f32x4){0.f, 0.f, 0.f, 0.f};

  for (int k0 = 0; k0 < K_; k0 += 64) {
    __syncthreads();  // previous iteration's LDS reads done
#pragma unroll
    for (int s = 0; s < 4; ++s) {
      const int q = w * 4 + s;  // 16 segments of 1 KiB each per matrix
      const u16* ga = Ab + (size_t)(m0 + q * 8 + lrow) * K_ + k0 + lcol;
      const u16* gb = Bb + (size_t)(n0 + q * 8 + lrow) * K_ + k0 + lcol;
      __builtin_amdgcn_global_load_lds((const __attribute__((address_space(1))) void*)ga,
                                       (__attribute__((address_space(3))) void*)(As + q * 512),
                                       16, 0, 0);
      __builtin_amdgcn_global_load_lds((const __attribute__((address_space(1))) void*)gb,
                                       (__attribute__((address_space(3))) void*)(Bs + q * 512),
                                       16, 0, 0);
    }
    __syncthreads();  // compiler drains vmcnt before barrier -> LDS tiles ready
#pragma unroll
    for (int kk = 0; kk < 64; kk += 32) {
      bf16x8 af[4], bfr[4];
#pragma unroll
      for (int i = 0; i < 4; ++i) af[i]  = *(const bf16x8*)(As + (wm + i * 16 + r) * 64 + kk + ko);
#pragma unroll
      for (int j = 0; j < 4; ++j) bfr[j] = *(const bf16x8*)(Bs + (wn + j * 16 + r) * 64 + kk + ko);
#pragma unroll
      for (int i = 0; i < 4; ++i)
#pragma unroll
        for (int j = 0; j < 4; ++j)
          acc[i][j] = __builtin_amdgcn_mfma_f32_16x16x32_bf16(af[i], bfr[j], acc[i][j], 0, 0, 0);
    }
  }

  // Epilogue: whole 128-wide tile lies in one segment of {Z,F,O} (128 | 1024).
  const int seg = n0 >> 10;
  const int nh0 = (n0 & 1023) + wn;
  float* dst = (seg == 0) ? zt : (seg == 1 ? Cf : Ho);
#pragma unroll
  for (int i = 0; i < 4; ++i) {
#pragma unroll
    for (int j = 0; j < 4; ++j) {
      const int nn = nh0 + j * 16 + (l & 15);
      const float bv = bias[seg * 1024 + nn];
#pragma unroll
      for (int rr = 0; rr < 4; ++rr) {
        const int mm = m0 + wm + i * 16 + (l >> 4) * 4 + rr;  // C/D: row=(lane>>4)*4+reg
        const float v = acc[i][j][rr] + bv;
        const float av = (seg == 0) ? tanh_(v) : sigmoid_(v);
        dst[(size_t)mm * H_ + nn] = av;
      }
    }
  }
}

// ---- scan pass A: per-chunk (prod(1-f), local c_end with c_in = 0) ----------
// float2 per thread: 8 B/lane loads (G13), grid (CH_/512, NC_) -> 16 waves/CU.
__global__ void scanA(const float* __restrict__ Cf, const float* __restrict__ zt,
                      float* __restrict__ ckA, float* __restrict__ ckC) {
  const int ch2 = blockIdx.x * 256 + threadIdx.x;   // float2 channel index
  const int j   = blockIdx.y;
  size_t base2 = (size_t)j * T_ * (CH_ / 2) + ch2;
  const float2* Cf2 = (const float2*)Cf;
  const float2* zt2 = (const float2*)zt;
  float2 A = {1.f, 1.f}, c = {0.f, 0.f};
  for (int tt = 0; tt < T_; ++tt) {
    const float2 f = Cf2[base2];
    const float2 z = zt2[base2];
    const float omx = 1.f - f.x, omy = 1.f - f.y;
    c.x = f.x * z.x + omx * c.x;
    c.y = f.y * z.y + omy * c.y;
    A.x *= omx;
    A.y *= omy;
    base2 += CH_ / 2;
  }
  ((float2*)ckA)[(size_t)j * (CH_ / 2) + ch2] = A;
  ((float2*)ckC)[(size_t)j * (CH_ / 2) + ch2] = c;
}

// ---- scan combine: sequential over NC_ chunks, seeded with hidden -----------
// 64-thread blocks spread over 128 CUs (latency chain, want breadth not depth).
__global__ void scanComb(const float* __restrict__ ckA, const float* __restrict__ ckC,
                         const float* __restrict__ hidden, float* __restrict__ carry) {
  const int ch = blockIdx.x * 64 + threadIdx.x;
  float c = hidden[ch];
  for (int j = 0; j < NC_; ++j) {
    carry[j * CH_ + ch] = c;              // c entering chunk j
    c = ckC[j * CH_ + ch] + ckA[j * CH_ + ch] * c;
  }
}

// ---- scan pass B: replay with true carry; write C and H in place ------------
__global__ void scanB(float* __restrict__ Cf,          // in: sigm(F), out: C
                      const float* __restrict__ zt,    // tanh(Z)
                      float* __restrict__ Ho,          // in: sigm(O), out: H
                      float* __restrict__ Clast,       // [CH_]
                      const float* __restrict__ carry) {
  const int ch2 = blockIdx.x * 256 + threadIdx.x;
  const int j   = blockIdx.y;
  size_t base2 = (size_t)j * T_ * (CH_ / 2) + ch2;
  float2* Cf2 = (float2*)Cf;
  const float2* zt2 = (const float2*)zt;
  float2* Ho2 = (float2*)Ho;
  float2 c = ((const float2*)carry)[(size_t)j * (CH_ / 2) + ch2];
  for (int tt = 0; tt < T_; ++tt) {
    const float2 f  = Cf2[base2];
    const float2 z  = zt2[base2];
    const float2 so = Ho2[base2];
    c.x = f.x * z.x + (1.f - f.x) * c.x;
    c.y = f.y * z.y + (1.f - f.y) * c.y;
    Cf2[base2] = c;
    Ho2[base2] = float2{so.x * c.x, so.y * c.y};
    base2 += CH_ / 2;
  }
  if (j == NC_ - 1) ((float2*)Clast)[ch2] = c;
}

extern "C" void kernel_launch(void* const* d_in, const int* in_sizes, int n_in,
                              void* d_out, int out_size, void* d_ws, size_t ws_size,
                              hipStream_t stream) {
  const float* X    = (const float*)d_in[0];   // [S,B,IN]
  const float* hid  = (const float*)d_in[1];   // [B,H]
  const float* W    = (const float*)d_in[2];   // [3H,IN]
  const float* bias = (const float*)d_in[3];   // [3H]

  float* out   = (float*)d_out;
  float* Ho    = out;                          // H       [S,B,H]
  float* Clast = out + (size_t)M_ * H_;        // C[-1:]  [1,B,H]
  float* Cf    = Clast + CH_;                  // C       [S,B,H]

  char* ws = (char*)d_ws;
  u16*  Xb    = (u16*)ws;                      //  67108864 B bf16 X
  u16*  Wb    = (u16*)(ws + 67108864);         //   6291456 B bf16 W
  float* zt   = (float*)(ws + 73400320);       // 134217728 B tanh(Z)
  float* ckA  = (float*)(ws + 207618048);      //   2097152 B
  float* ckC  = (float*)(ws + 209715200);      //   2097152 B
  float* carry= (float*)(ws + 211812352);      //   2097152 B  (total ~204 MiB)

  cvt_bf16_kernel<<<(M_ * K_ / 8 + 255) / 256, 256, 0, stream>>>(X, Xb, M_ * K_ / 8);
  cvt_bf16_kernel<<<(N_ * K_ / 8 + 255) / 256, 256, 0, stream>>>(W, Wb, N_ * K_ / 8);
  gemm_act<<<dim3(N_ / 128, M_ / 128), 256, 0, stream>>>(Xb, Wb, bias, zt, Cf, Ho);
  scanA<<<dim3(CH_ / 512, NC_), 256, 0, stream>>>(Cf, zt, ckA, ckC);
  scanComb<<<CH_ / 64, 64, 0, stream>>>(ckA, ckC, hid, carry);
  scanB<<<dim3(CH_ / 512, NC_), 256, 0, stream>>>(Cf, zt, Ho, Clast, carry);
}